// Round 1
// baseline (357.244 us; speedup 1.0000x reference)
//
#include <hip/hip_runtime.h>
#include <hip/hip_bf16.h>
#include <stdint.h>

#define B_    8
#define S_    4096
#define D_    1536
#define ORG_  4
#define OUT_  2048

typedef __bf16 bf16;
typedef __attribute__((ext_vector_type(8))) bf16  bf16x8;
typedef __attribute__((ext_vector_type(4))) float f32x4;

#define BM 128
#define BN 128
#define BK 32

// ---------------- convert x: f32 -> bf16 (8 elems/thread/iter) --------------
__global__ void k_cvt_x(const float* __restrict__ x, bf16* __restrict__ xb, long n8) {
  long i = (long)blockIdx.x * blockDim.x + threadIdx.x;
  long stride = (long)gridDim.x * blockDim.x;
  for (; i < n8; i += stride) {
    const float4* p = (const float4*)(x + i * 8);
    float4 a = p[0];
    float4 b = p[1];
    bf16x8 v;
    v[0] = (bf16)a.x; v[1] = (bf16)a.y; v[2] = (bf16)a.z; v[3] = (bf16)a.w;
    v[4] = (bf16)b.x; v[5] = (bf16)b.y; v[6] = (bf16)b.z; v[7] = (bf16)b.w;
    *(bf16x8*)(xb + i * 8) = v;
  }
}

// ------ convert + transpose w: f32 [ORG][D][OUT] -> bf16 [ORG][OUT][D] ------
__global__ void k_cvt_wT(const float* __restrict__ w, bf16* __restrict__ wt) {
  __shared__ float tile[32][33];
  int org = blockIdx.z;
  int n0 = blockIdx.x * 32;   // OUT dim
  int d0 = blockIdx.y * 32;   // D dim
  const float* wsrc = w + (size_t)org * D_ * OUT_;
  bf16* wdst = wt + (size_t)org * OUT_ * D_;
  int tx = threadIdx.x, ty = threadIdx.y;
#pragma unroll
  for (int j = 0; j < 32; j += 8)
    tile[ty + j][tx] = wsrc[(size_t)(d0 + ty + j) * OUT_ + (n0 + tx)];
  __syncthreads();
#pragma unroll
  for (int j = 0; j < 32; j += 8)
    wdst[(size_t)(n0 + ty + j) * D_ + (d0 + tx)] = (bf16)tile[tx][ty + j];
}

// ---------------- bf16 MFMA GEMM, m97-style 128x128 tile --------------------
// A = xb[batch] : [S][D]  (row-major, contiguous K)
// B = wt[org]   : [OUT][D] (row-major, contiguous K)  -> C[m][n] = sum_k A*B
__global__ __launch_bounds__(256, 2)
void k_gemm(const bf16* __restrict__ xb, const bf16* __restrict__ wt,
            const int* __restrict__ oidx, const float* __restrict__ bias,
            float* __restrict__ out) {
  __shared__ bf16 As[BM * BK];
  __shared__ bf16 Bs[BN * BK];

  const int batch = blockIdx.y;
  const int ntn = OUT_ / BN;          // 16
  const int tm = blockIdx.x / ntn;
  const int tn = blockIdx.x % ntn;
  const int m0 = tm * BM, n0 = tn * BN;
  const int org = oidx[batch];

  const bf16* Ag = xb + (size_t)batch * S_ * D_ + (size_t)m0 * D_;
  const bf16* Bg = wt + (size_t)org * OUT_ * D_ + (size_t)n0 * D_;

  const int t = threadIdx.x;
  const int lane = t & 63, wave = t >> 6;
  const int wr = wave >> 1, wc = wave & 1;   // wave sub-tile: rows wr*64, cols wc*64
  const int srow = t >> 2;                   // staging row within half-tile (0..63)
  const int sk = (t & 3) * 8;                // staging k offset (bf16 elems)
  const int lm = lane & 15, lk = lane >> 4;  // fragment row/col, k-group

  f32x4 acc[4][4];
#pragma unroll
  for (int i = 0; i < 4; ++i)
#pragma unroll
    for (int j = 0; j < 4; ++j)
      acc[i][j] = (f32x4){0.f, 0.f, 0.f, 0.f};

  for (int kt = 0; kt < D_ / BK; ++kt) {
    const int kb = kt * BK;
    // stage A,B tiles: 2 calls each, 256 threads x 16B = 4KB/call, tile = 8KB
#pragma unroll
    for (int c = 0; c < 2; ++c) {
      __builtin_amdgcn_global_load_lds(
          (__attribute__((address_space(1))) void*)(Ag + (size_t)(c * 64 + srow) * D_ + kb + sk),
          (__attribute__((address_space(3))) void*)((char*)As + c * 4096 + wave * 1024),
          16, 0, 0);
      __builtin_amdgcn_global_load_lds(
          (__attribute__((address_space(1))) void*)(Bg + (size_t)(c * 64 + srow) * D_ + kb + sk),
          (__attribute__((address_space(3))) void*)((char*)Bs + c * 4096 + wave * 1024),
          16, 0, 0);
    }
    __syncthreads();

    bf16x8 a[4], b[4];
#pragma unroll
    for (int i = 0; i < 4; ++i)
      a[i] = *(const bf16x8*)&As[(wr * 64 + i * 16 + lm) * BK + lk * 8];
#pragma unroll
    for (int j = 0; j < 4; ++j)
      b[j] = *(const bf16x8*)&Bs[(wc * 64 + j * 16 + lm) * BK + lk * 8];

#pragma unroll
    for (int i = 0; i < 4; ++i)
#pragma unroll
      for (int j = 0; j < 4; ++j)
        acc[i][j] = __builtin_amdgcn_mfma_f32_16x16x32_bf16(a[i], b[j], acc[i][j], 0, 0, 0);

    __syncthreads();
  }

  // epilogue: C/D layout col = lane&15, row = (lane>>4)*4 + reg
  float* Og = out + (size_t)batch * S_ * OUT_ + (size_t)m0 * OUT_ + n0;
  const float* bb = bias + (size_t)org * OUT_ + n0;
#pragma unroll
  for (int i = 0; i < 4; ++i) {
#pragma unroll
    for (int j = 0; j < 4; ++j) {
      const int col = wc * 64 + j * 16 + lm;
      const float bv = bb[col];
#pragma unroll
      for (int r = 0; r < 4; ++r) {
        const int row = wr * 64 + i * 16 + lk * 4 + r;
        Og[(size_t)row * OUT_ + col] = acc[i][j][r] + bv;
      }
    }
  }
}

// ---------------- fallback: naive fp32 (only if ws too small) ---------------
__global__ void k_gemm_fallback(const float* __restrict__ x, const int* __restrict__ oidx,
                                const float* __restrict__ w, const float* __restrict__ bias,
                                float* __restrict__ out) {
  // grid (OUT/64, S/4, B), block (64,4)
  const int b = blockIdx.z;
  const int org = oidx[b];
  const int n = blockIdx.x * 64 + threadIdx.x;
  const int m = blockIdx.y * 4 + threadIdx.y;
  const float* xr = x + ((size_t)b * S_ + m) * D_;
  const float* wp = w + (size_t)org * D_ * OUT_ + n;
  float acc = 0.f;
  for (int k = 0; k < D_; ++k) acc += xr[k] * wp[(size_t)k * OUT_];
  out[((size_t)b * S_ + m) * OUT_ + n] = acc + bias[(size_t)org * OUT_ + n];
}

extern "C" void kernel_launch(void* const* d_in, const int* in_sizes, int n_in,
                              void* d_out, int out_size, void* d_ws, size_t ws_size,
                              hipStream_t stream) {
  const float* x    = (const float*)d_in[0];
  const int*   oidx = (const int*)d_in[1];
  const float* w    = (const float*)d_in[2];
  const float* bias = (const float*)d_in[3];
  float* out = (float*)d_out;

  const size_t xb_elems = (size_t)B_ * S_ * D_;      // 50,331,648
  const size_t wt_elems = (size_t)ORG_ * OUT_ * D_;  // 12,582,912
  const size_t need = (xb_elems + wt_elems) * sizeof(bf16);  // ~126 MB

  if (ws_size < need) {
    dim3 g(OUT_ / 64, S_ / 4, B_);
    k_gemm_fallback<<<g, dim3(64, 4), 0, stream>>>(x, oidx, w, bias, out);
    return;
  }

  bf16* xb = (bf16*)d_ws;
  bf16* wt = xb + xb_elems;  // byte offset 100,663,296 (16B aligned)

  k_cvt_x<<<2048, 256, 0, stream>>>(x, xb, (long)(xb_elems / 8));
  dim3 gt(OUT_ / 32, D_ / 32, ORG_);
  k_cvt_wT<<<gt, dim3(32, 8), 0, stream>>>(w, wt);
  dim3 gg((S_ / BM) * (OUT_ / BN), B_);
  k_gemm<<<gg, 256, 0, stream>>>(xb, wt, oidx, bias, out);
}

// Round 2
// 313.151 us; speedup vs baseline: 1.1408x; 1.1408x over previous
//
#include <hip/hip_runtime.h>
#include <hip/hip_bf16.h>
#include <stdint.h>

#define B_    8
#define S_    4096
#define D_    1536
#define ORG_  4
#define OUT_  2048

typedef __bf16 bf16;
typedef __attribute__((ext_vector_type(8))) bf16  bf16x8;
typedef __attribute__((ext_vector_type(4))) float f32x4;

#define BK64 64
#define NKT  (D_ / BK64)   // 24 K-tiles

// ---------------- convert x: f32 -> bf16 (8 elems/thread/iter) --------------
__global__ void k_cvt_x(const float* __restrict__ x, bf16* __restrict__ xb, long n8) {
  long i = (long)blockIdx.x * blockDim.x + threadIdx.x;
  long stride = (long)gridDim.x * blockDim.x;
  for (; i < n8; i += stride) {
    const float4* p = (const float4*)(x + i * 8);
    float4 a = p[0];
    float4 b = p[1];
    bf16x8 v;
    v[0] = (bf16)a.x; v[1] = (bf16)a.y; v[2] = (bf16)a.z; v[3] = (bf16)a.w;
    v[4] = (bf16)b.x; v[5] = (bf16)b.y; v[6] = (bf16)b.z; v[7] = (bf16)b.w;
    *(bf16x8*)(xb + i * 8) = v;
  }
}

// ------ convert + transpose w: f32 [ORG][D][OUT] -> bf16 [ORG][OUT][D] ------
__global__ void k_cvt_wT(const float* __restrict__ w, bf16* __restrict__ wt) {
  __shared__ float tile[32][33];
  int org = blockIdx.z;
  int n0 = blockIdx.x * 32;   // OUT dim
  int d0 = blockIdx.y * 32;   // D dim
  const float* wsrc = w + (size_t)org * D_ * OUT_;
  bf16* wdst = wt + (size_t)org * OUT_ * D_;
  int tx = threadIdx.x, ty = threadIdx.y;
#pragma unroll
  for (int j = 0; j < 32; j += 8)
    tile[ty + j][tx] = wsrc[(size_t)(d0 + ty + j) * OUT_ + (n0 + tx)];
  __syncthreads();
#pragma unroll
  for (int j = 0; j < 32; j += 8)
    wdst[(size_t)(n0 + ty + j) * D_ + (d0 + tx)] = (bf16)tile[tx][ty + j];
}

// ------------- 256x256 8-phase bf16 MFMA GEMM (T1+T2+T3+T4+T5) --------------
// A = xb[batch] : [S][D] row-major;  B = wt[org] : [OUT][D] row-major (B^T form)
// C[m][n] = sum_k A[m][k]*B[n][k]  + bias[n]
__global__ __launch_bounds__(512, 2)
void k_gemm256(const bf16* __restrict__ xb, const bf16* __restrict__ wt,
               const int* __restrict__ oidx, const float* __restrict__ bias,
               float* __restrict__ out) {
  __shared__ __align__(16) char smem[131072];   // A: 2x32KB, B: 2x32KB
  char* const ldsA = smem;
  char* const ldsB = smem + 65536;

  const int batch = blockIdx.y;
  const int bx = blockIdx.x;
  // T1: XCD-aware swizzle (128 tiles % 8 == 0 -> simple bijective form).
  // Each XCD gets one tn column (shares the 786KB w-panel in its L2).
  const int swz = (bx & 7) * 16 + (bx >> 3);
  const int tn = swz >> 4, tm = swz & 15;
  const int m0 = tm * 256, n0 = tn * 256;
  const int org = oidx[batch];

  const bf16* Ag = xb + (size_t)batch * S_ * D_ + (size_t)m0 * D_;
  const bf16* Bg = wt + (size_t)org * OUT_ * D_ + (size_t)n0 * D_;

  const int tid  = threadIdx.x;
  const int lane = tid & 63, wv = tid >> 6;
  const int wr = wv >> 2, wc = wv & 3;        // 2x4 wave grid, per-wave 128x64 out
  const int lm = lane & 15, lk = lane >> 4;

  // T2: XOR swizzle byte ^= (row&7)<<4. Read-side offsets within a 128B row:
  const int xo0 = (lk * 16) ^ ((lm & 7) << 4);        // kk=0
  const int xo1 = (64 + lk * 16) ^ ((lm & 7) << 4);   // kk=1
  const int arow = (wr * 128 + lm) * 128;             // + mi*2048
  const int brow = (wc * 64  + lm) * 128;             // + ni*2048

  // Stage-side: linear LDS dest (gload_lds is base+lane*16), inverse-swizzled
  // per-lane GLOBAL source: row = blk*64 + tid>>3, colchunk = (tid&7)^((tid>>3)&7)
  const int srow = tid >> 3;                          // 0..63
  const int scol = ((tid & 7) ^ ((tid >> 3) & 7)) << 3;  // bf16 elements
  const int soff = wv * 1024;                         // wave-uniform LDS offset

#define LDA(v, mi, kk) (*(const bf16x8*)(ldsA + (v)*32768 + arow + (mi)*2048 + ((kk) ? xo1 : xo0)))
#define LDB(v, ni, kk) (*(const bf16x8*)(ldsB + (v)*32768 + brow + (ni)*2048 + ((kk) ? xo1 : xo0)))

#define STAGE_HALF(gptr, ldsbase, h, kb) do {                                            \
    __builtin_amdgcn_global_load_lds(                                                    \
      (__attribute__((address_space(1))) void*)((gptr) + (size_t)((h)*128 + srow) * D_ + (kb) + scol), \
      (__attribute__((address_space(3))) void*)((ldsbase) + (h)*16384 + soff), 16, 0, 0);\
    __builtin_amdgcn_global_load_lds(                                                    \
      (__attribute__((address_space(1))) void*)((gptr) + (size_t)((h)*128 + 64 + srow) * D_ + (kb) + scol), \
      (__attribute__((address_space(3))) void*)((ldsbase) + (h)*16384 + 8192 + soff), 16, 0, 0); \
  } while (0)

#define SBAR()  __builtin_amdgcn_s_barrier()
#define LGK0()  asm volatile("s_waitcnt lgkmcnt(0)" ::: "memory")
#define VMC4()  asm volatile("s_waitcnt vmcnt(4)" ::: "memory")
#define VMC0()  asm volatile("s_waitcnt vmcnt(0)" ::: "memory")
#define PRIO(p) __builtin_amdgcn_s_setprio(p)

  bf16x8 a[4][2], b0[2][2], b1[2][2];
  f32x4 acc[8][4];
#pragma unroll
  for (int m = 0; m < 8; ++m)
#pragma unroll
    for (int n = 0; n < 4; ++n) acc[m][n] = (f32x4){0.f, 0.f, 0.f, 0.f};

#define READ_A(v, mb) do { _Pragma("unroll") for (int m = 0; m < 4; ++m) { \
    a[m][0] = LDA(v, (mb) + m, 0); a[m][1] = LDA(v, (mb) + m, 1); } } while (0)
#define READ_B(v, nb, bb) do { _Pragma("unroll") for (int n = 0; n < 2; ++n) { \
    bb[n][0] = LDB(v, (nb) + n, 0); bb[n][1] = LDB(v, (nb) + n, 1); } } while (0)
#define MFMA_Q(mb, nb, bb) do { \
    _Pragma("unroll") for (int m = 0; m < 4; ++m) \
    _Pragma("unroll") for (int n = 0; n < 2; ++n) \
    _Pragma("unroll") for (int kk = 0; kk < 2; ++kk) \
      acc[(mb)+m][(nb)+n] = __builtin_amdgcn_mfma_f32_16x16x32_bf16( \
          a[m][kk], bb[n][kk], acc[(mb)+m][(nb)+n], 0, 0, 0); } while (0)

  // ---- prologue: tile0 B+A, tile1 B (6 halves = 12 loads); allow newest 2
  // halves (tile1 B) outstanding at the barrier.
  STAGE_HALF(Bg, ldsB, 0, 0);
  STAGE_HALF(Bg, ldsB, 1, 0);
  STAGE_HALF(Ag, ldsA, 0, 0);
  STAGE_HALF(Ag, ldsA, 1, 0);
  STAGE_HALF(Bg, ldsB + 32768, 0, BK64);
  STAGE_HALF(Bg, ldsB + 32768, 1, BK64);
  VMC4();
  SBAR();

  for (int i = 0; i < NKT / 2; ++i) {
    const int k1 = (2 * i + 1) * BK64;               // always valid (<= 23)
    int t2 = 2 * i + 2; if (t2 > NKT - 1) t2 = NKT - 1;   // clamp, never skip:
    int t3 = 2 * i + 3; if (t3 > NKT - 1) t3 = NKT - 1;   // keeps vmcnt math exact
    const int k2 = t2 * BK64, k3 = t3 * BK64;

    // P1: compute t=2i quad(m0-3 x n0-1); stage A-half0(2i+1) -> buf1
    READ_A(0, 0); READ_B(0, 0, b0);
    STAGE_HALF(Ag, ldsA + 32768, 0, k1);
    SBAR(); LGK0();
    PRIO(1); MFMA_Q(0, 0, b0); PRIO(0);
    SBAR();
    // P2: quad(m0-3 x n2-3); stage A-half1(2i+1) -> buf1
    READ_B(0, 2, b1);
    STAGE_HALF(Ag, ldsA + 32768, 1, k1);
    SBAR(); LGK0();
    PRIO(1); MFMA_Q(0, 2, b1); PRIO(0);
    SBAR();
    // P3: quad(m4-7 x n0-1); stage B-half0(2i+2) -> buf0 (B(2i) free after P2)
    READ_A(0, 4);
    STAGE_HALF(Bg, ldsB, 0, k2);
    SBAR(); LGK0();
    PRIO(1); MFMA_Q(4, 0, b0); PRIO(0);
    SBAR();
    // P4: quad(m4-7 x n2-3); stage B-half1(2i+2); checkpoint vmcnt(4)
    STAGE_HALF(Bg, ldsB, 1, k2);
    SBAR();
    PRIO(1); MFMA_Q(4, 2, b1); PRIO(0);
    VMC4();
    SBAR();
    // P5: compute t=2i+1 quad(m0-3 x n0-1); stage A-half0(2i+2) -> buf0
    READ_A(1, 0); READ_B(1, 0, b0);
    STAGE_HALF(Ag, ldsA, 0, k2);
    SBAR(); LGK0();
    PRIO(1); MFMA_Q(0, 0, b0); PRIO(0);
    SBAR();
    // P6: quad(m0-3 x n2-3); stage A-half1(2i+2) -> buf0
    READ_B(1, 2, b1);
    STAGE_HALF(Ag, ldsA, 1, k2);
    SBAR(); LGK0();
    PRIO(1); MFMA_Q(0, 2, b1); PRIO(0);
    SBAR();
    // P7: quad(m4-7 x n0-1); stage B-half0(2i+3) -> buf1 (B(2i+1) free after P6)
    READ_A(1, 4);
    STAGE_HALF(Bg, ldsB + 32768, 0, k3);
    SBAR(); LGK0();
    PRIO(1); MFMA_Q(4, 0, b0); PRIO(0);
    SBAR();
    // P8: quad(m4-7 x n2-3); stage B-half1(2i+3); checkpoint vmcnt(4)
    STAGE_HALF(Bg, ldsB + 32768, 1, k3);
    SBAR();
    PRIO(1); MFMA_Q(4, 2, b1); PRIO(0);
    VMC4();
    SBAR();
  }

  VMC0();  // drain trailing (clamped) stages before endpgm

  // epilogue: C/D layout col = lane&15, row = (lane>>4)*4 + reg
  float* Og = out + (size_t)batch * S_ * OUT_ + (size_t)m0 * OUT_ + n0;
  const float* bbase = bias + (size_t)org * OUT_ + n0;
#pragma unroll
  for (int n = 0; n < 4; ++n) {
    const int col = wc * 64 + n * 16 + lm;
    const float bv = bbase[col];
#pragma unroll
    for (int m = 0; m < 8; ++m) {
#pragma unroll
      for (int r = 0; r < 4; ++r) {
        const int row = wr * 128 + m * 16 + lk * 4 + r;
        Og[(size_t)row * OUT_ + col] = acc[m][n][r] + bv;
      }
    }
  }
#undef LDA
#undef LDB
#undef STAGE_HALF
#undef SBAR
#undef LGK0
#undef VMC4
#undef VMC0
#undef PRIO
#undef READ_A
#undef READ_B
#undef MFMA_Q
}

// ---------------- fallback: naive fp32 (only if ws too small) ---------------
__global__ void k_gemm_fallback(const float* __restrict__ x, const int* __restrict__ oidx,
                                const float* __restrict__ w, const float* __restrict__ bias,
                                float* __restrict__ out) {
  const int b = blockIdx.z;
  const int org = oidx[b];
  const int n = blockIdx.x * 64 + threadIdx.x;
  const int m = blockIdx.y * 4 + threadIdx.y;
  const float* xr = x + ((size_t)b * S_ + m) * D_;
  const float* wp = w + (size_t)org * D_ * OUT_ + n;
  float acc = 0.f;
  for (int k = 0; k < D_; ++k) acc += xr[k] * wp[(size_t)k * OUT_];
  out[((size_t)b * S_ + m) * OUT_ + n] = acc + bias[(size_t)org * OUT_ + n];
}

extern "C" void kernel_launch(void* const* d_in, const int* in_sizes, int n_in,
                              void* d_out, int out_size, void* d_ws, size_t ws_size,
                              hipStream_t stream) {
  const float* x    = (const float*)d_in[0];
  const int*   oidx = (const int*)d_in[1];
  const float* w    = (const float*)d_in[2];
  const float* bias = (const float*)d_in[3];
  float* out = (float*)d_out;

  const size_t xb_elems = (size_t)B_ * S_ * D_;      // 50,331,648
  const size_t wt_elems = (size_t)ORG_ * OUT_ * D_;  // 12,582,912
  const size_t need = (xb_elems + wt_elems) * sizeof(bf16);  // ~126 MB

  if (ws_size < need) {
    dim3 g(OUT_ / 64, S_ / 4, B_);
    k_gemm_fallback<<<g, dim3(64, 4), 0, stream>>>(x, oidx, w, bias, out);
    return;
  }

  bf16* xb = (bf16*)d_ws;
  bf16* wt = xb + xb_elems;

  k_cvt_x<<<2048, 256, 0, stream>>>(x, xb, (long)(xb_elems / 8));
  dim3 gt(OUT_ / 32, D_ / 32, ORG_);
  k_cvt_wT<<<gt, dim3(32, 8), 0, stream>>>(w, wt);
  dim3 gg(128, B_);
  k_gemm256<<<gg, 512, 0, stream>>>(xb, wt, oidx, bias, out);
}